// Round 11
// baseline (73.742 us; speedup 1.0000x reference)
//
#include <hip/hip_runtime.h>
#include <math.h>

// Problem constants (fixed by setup_inputs)
constexpr int BB = 512;    // batch (GEMM M)
constexpr int DD = 512;    // features (GEMM K)
constexpr int CC = 1000;   // classes
constexpr int CP = 1024;   // padded classes (GEMM N)
constexpr int RP = 528;    // padded row length (shorts): 1056 B, 16B-aligned,
                           // breaks 256B/1KB channel periodicity
constexpr int NDC = 8;     // norm d-chunks (64 d each)
constexpr float EPSF = 0.3f;

// TWO launches (best structure: R8/R10 lineage; coop grid.sync was a 2.5x
// regression — ~125 us on 8-XCD gfx950).
// K[b,c]^2 = nj[b] + nc[c] - 2*dot(col_jb, col_c); dot via bf16 MFMA.
// Q[b,:] == row j_b of transposed Wt and nj[b] == nc[j_b] -> no gather pass.
//   lm_build : blocks 0-127  : argmax/ymax per row (1 wave/row) + fused y->out
//              blocks 128-255: kW -> Wt (bf16 transpose via LDS, zero-padded,
//              coalesced 16B writes) + fp32 column-norm chunks, c-major
//   lm_gemm  : 2048 blocks x 128 thr: one 16x16 (batch x class) tile per
//              block, K split across the 2 waves (halved load burst + MFMA
//              chain, 4 waves/SIMD occupancy), LDS combine, epilogue on wave
//              0: float4 norm loads, candidates, butterfly row-max, atomicMax
//              (float-as-int; all candidates positive — validated R5-R10).
//
// ws layout (16B-aligned):
//   Wt    [1024*528] ushort @ 0        (1081 KB)
//   normc [1024*8]   float  @ 1088 KB  (32 KB, c-major: normc[c*8+dc])
//   wj    [512]      int    @ +32 KB
//   wymax [512]      float  @ +2 KB

using short8 = __attribute__((ext_vector_type(8))) short;
using us8    = __attribute__((ext_vector_type(8))) unsigned short;
using f32x4  = __attribute__((ext_vector_type(4))) float;

__device__ inline unsigned short f2bf(float f) {   // RNE float->bf16
  unsigned u = __float_as_uint(f);
  return (unsigned short)((u + 0x7FFFu + ((u >> 16) & 1u)) >> 16);
}

__global__ __launch_bounds__(256) void lm_build(const float* __restrict__ y,
                                                const float* __restrict__ kW,
                                                unsigned short* __restrict__ Wt,
                                                float* __restrict__ normc,
                                                int* __restrict__ wj,
                                                float* __restrict__ wymax,
                                                float* __restrict__ out) {
  const int t = threadIdx.x;
  const int w = t >> 6, lane = t & 63;

  if (blockIdx.x < 128) {
    // ---------- argmax/ymax, one wave per row, + fused y->out copy ----------
    const int b = blockIdx.x * 4 + w;
    const float* yr = y + (size_t)b * CC;
    float bv = -INFINITY; int bi = 0;
    #pragma unroll
    for (int k = 0; k < 4; ++k) {
      const int c4 = (lane + k * 64) * 4;   // ascending per lane -> '>' keeps lowest
      if (c4 < CC) {
        const float4 v = *(const float4*)(yr + c4);
        if (v.x > bv) { bv = v.x; bi = c4; }
        if (v.y > bv) { bv = v.y; bi = c4 + 1; }
        if (v.z > bv) { bv = v.z; bi = c4 + 2; }
        if (v.w > bv) { bv = v.w; bi = c4 + 3; }
        float* orow = out + (size_t)b * (CC + 1) + c4;  // scalar stores (row stride 1001)
        orow[0] = v.x; orow[1] = v.y; orow[2] = v.z; orow[3] = v.w;
      }
    }
    #pragma unroll
    for (int off = 32; off > 0; off >>= 1) {
      const float ov = __shfl_down(bv, off);
      const int   oi = __shfl_down(bi, off);
      if (ov > bv || (ov == bv && oi < bi)) { bv = ov; bi = oi; }
    }
    if (lane == 0) { wj[b] = bi; wymax[b] = bv; }
  } else {
    // ---------- transpose kW -> Wt (LDS-staged) + fp32 norm chunks ----------
    __shared__ float nsum[4][64];
    __shared__ __align__(16) unsigned short tile[64][72];  // 64c x 64d (+pad)
    const int blk = blockIdx.x - 128;    // 0..127
    const int cs = blk & 15, dc = blk >> 4;   // 16 c-slices x 8 d-chunks
    const int c0 = cs * 64, d0 = dc * 64;
    const int c = c0 + lane;
    const bool cok = (c < CC);
    float s = 0.f;
    #pragma unroll 8
    for (int it = 0; it < 16; ++it) {
      const int dd = w + it * 4;                    // 0..63
      const float v = cok ? kW[(size_t)(d0 + dd) * CC + c] : 0.f;
      s += v * v;
      tile[lane][dd] = f2bf(v);
    }
    nsum[w][lane] = s;
    __syncthreads();
    if (w == 0)                                      // c-major norm chunk
      normc[(size_t)c * NDC + dc] = nsum[0][lane] + nsum[1][lane] + nsum[2][lane] + nsum[3][lane];
    // coalesced 16B writes of the transposed tile
    #pragma unroll
    for (int k = 0; k < 2; ++k) {
      const int lin = t * 2 + k;                    // 0..511
      const int cc = lin >> 3, ch = lin & 7;
      *(us8*)(Wt + (size_t)(c0 + cc) * RP + d0 + ch * 8) =
          *(const us8*)(&tile[cc][ch * 8]);
    }
  }
}

__global__ __launch_bounds__(128) void lm_gemm(const unsigned short* __restrict__ Wt,
                                               const float* __restrict__ y,
                                               const float* __restrict__ normc,
                                               const int* __restrict__ wj,
                                               const float* __restrict__ wymax,
                                               float* __restrict__ out) {
  __shared__ __align__(16) f32x4 sacc[64];

  const int t = threadIdx.x;
  const int lane = t & 63;
  const int kw = t >> 6;                        // K-half 0/1
  const int tile = blockIdx.x;                  // 0..2047
  const int m0 = (tile >> 6) * 16;              // 32 m-tiles (batch)
  const int n0 = (tile & 63) * 16;              // 64 n-tiles (classes)

  const int fr = lane & 15;            // A: m-row / B: n-row / C: col
  const int quad = lane >> 4;          // A/B: k-offset quad*8; C: row quad*4+reg

  const int ja = wj[m0 + fr];          // A-side: row j of Wt IS column j of kW
  const unsigned short* ap = Wt + (size_t)ja * RP + kw * 256 + quad * 8;
  const unsigned short* bp = Wt + (size_t)(n0 + fr) * RP + kw * 256 + quad * 8;

  // register-prefetch this wave's K-half (16 independent 16B loads)
  short8 af[8], bf[8];
  #pragma unroll
  for (int k = 0; k < 8; ++k) {
    af[k] = *(const short8*)(ap + k * 32);
    bf[k] = *(const short8*)(bp + k * 32);
  }
  // two accumulators: dependent-MFMA chain depth 4, not 8
  f32x4 a0 = {0.f, 0.f, 0.f, 0.f}, a1 = {0.f, 0.f, 0.f, 0.f};
  #pragma unroll
  for (int k = 0; k < 8; k += 2) {
    a0 = __builtin_amdgcn_mfma_f32_16x16x32_bf16(af[k],     bf[k],     a0, 0, 0, 0);
    a1 = __builtin_amdgcn_mfma_f32_16x16x32_bf16(af[k + 1], bf[k + 1], a1, 0, 0, 0);
  }
  f32x4 acc = a0 + a1;

  if (kw == 1) sacc[lane] = acc;
  __syncthreads();
  if (kw == 1) return;
  acc += sacc[lane];                   // combine K-halves

  // ---- fused epilogue (wave 0): candidates + butterfly row-max + atomicMax ----
  const int col = n0 + fr;             // class
  const bool cok = (col < CC);
  float nc = 0.f;
  if (cok) {
    const float4 na = *(const float4*)(normc + (size_t)col * NDC);
    const float4 nb = *(const float4*)(normc + (size_t)col * NDC + 4);
    nc = (na.x + na.y) + (na.z + na.w) + (nb.x + nb.y) + (nb.z + nb.w);
  }

  #pragma unroll
  for (int r = 0; r < 4; ++r) {
    const int row = m0 + quad * 4 + r; // batch
    float cd = -INFINITY;
    if (cok) {
      const int jr = wj[row];
      const float4 ja4 = *(const float4*)(normc + (size_t)jr * NDC);
      const float4 jb4 = *(const float4*)(normc + (size_t)jr * NDC + 4);
      const float nj = (ja4.x + ja4.y) + (ja4.z + ja4.w) + (jb4.x + jb4.y) + (jb4.z + jb4.w);
      const float yv = y[(size_t)row * CC + col];
      const float ym = wymax[row];
      const float k2 = nj + nc - 2.f * acc[r];
      cd = (yv == ym) ? -INFINITY : yv + EPSF * sqrtf(fmaxf(k2, 0.f) + 1e-10f);
    }
    #pragma unroll
    for (int m = 1; m < 16; m <<= 1)   // reduce over the 16 cols (same quad group)
      cd = fmaxf(cd, __shfl_xor(cd, m));
    if (fr == 0)                        // positive floats: int compare == float compare
      atomicMax((int*)(out + (size_t)row * (CC + 1) + CC), __float_as_int(cd));
  }
}

extern "C" void kernel_launch(void* const* d_in, const int* in_sizes, int n_in,
                              void* d_out, int out_size, void* d_ws, size_t ws_size,
                              hipStream_t stream) {
  const float* y  = (const float*)d_in[0];   // [512, 1000]
  const float* kW = (const float*)d_in[1];   // [512, 1000]
  float* out = (float*)d_out;                // [512, 1001]

  char* ws = (char*)d_ws;
  unsigned short* Wt = (unsigned short*)(ws);                   // 1024*528*2 = 1081 KB
  float* normc       = (float*)(ws + (1088 << 10));             // 32 KB
  int*   wjp         = (int*)(ws + (1120 << 10));               // 2 KB
  float* wymaxp      = (float*)(ws + (1122 << 10));             // 2 KB

  lm_build<<<256, 256, 0, stream>>>(y, kW, Wt, normc, wjp, wymaxp, out);
  lm_gemm<<<2048, 128, 0, stream>>>(Wt, y, normc, wjp, wymaxp, out);
}

// Round 12
// 73.067 us; speedup vs baseline: 1.0092x; 1.0092x over previous
//
#include <hip/hip_runtime.h>
#include <math.h>

// Problem constants (fixed by setup_inputs)
constexpr int BB = 512;    // batch (GEMM M)
constexpr int DD = 512;    // features (GEMM K)
constexpr int CC = 1000;   // classes
constexpr int CP = 1024;   // padded classes (GEMM N)
constexpr int RP = 528;    // padded row length (shorts): 1056 B, 16B-aligned,
                           // breaks 256B/1KB channel periodicity
constexpr int NDC = 8;     // norm d-chunks (64 d each)
constexpr float EPSF = 0.3f;

// TWO launches — best measured structure (R10 = 72.6 us). Session findings:
//   - coop grid.sync: +125 us on 8-XCD gfx950 (R9) — never again
//   - K-split gemm (2048x128): +1.1 us vs R10 (R11) — reverted
//   - dur_us is ~2/3 harness floor (268 MB ws re-poison fill @82% HBM peak
//     + reset dispatch train); kernels here are ~5 us total.
// K[b,c]^2 = nj[b] + nc[c] - 2*dot(col_jb, col_c); dot via bf16 MFMA.
// Q[b,:] == row j_b of transposed Wt and nj[b] == nc[j_b] -> no gather pass.
//   lm_build : blocks 0-127  : argmax/ymax per row (1 wave/row) + fused y->out
//              (4B-aligned dwordx4 stores); blocks 128-255: kW -> Wt (bf16
//              transpose via LDS, zero-padded, coalesced 16B writes) + fp32
//              column-norm chunks, c-major
//   lm_gemm  : 512 blocks x 256 thr, one 16x16 (batch x class) tile per wave;
//              32 fragments register-prefetched, 16 MFMAs in 2 indep chains;
//              epilogue: float4 norm loads, candidates, butterfly row-max,
//              atomicMax (float-as-int; candidates positive — valid R5-R11).
//
// ws layout (16B-aligned):
//   Wt    [1024*528] ushort @ 0        (1081 KB)
//   normc [1024*8]   float  @ 1088 KB  (32 KB, c-major: normc[c*8+dc])
//   wj    [512]      int    @ +32 KB
//   wymax [512]      float  @ +2 KB

using short8 = __attribute__((ext_vector_type(8))) short;
using us8    = __attribute__((ext_vector_type(8))) unsigned short;
using f32x4  = __attribute__((ext_vector_type(4))) float;
typedef float f4u __attribute__((ext_vector_type(4), aligned(4)));  // 4B-aligned float4

__device__ inline unsigned short f2bf(float f) {   // RNE float->bf16
  unsigned u = __float_as_uint(f);
  return (unsigned short)((u + 0x7FFFu + ((u >> 16) & 1u)) >> 16);
}

__global__ __launch_bounds__(256) void lm_build(const float* __restrict__ y,
                                                const float* __restrict__ kW,
                                                unsigned short* __restrict__ Wt,
                                                float* __restrict__ normc,
                                                int* __restrict__ wj,
                                                float* __restrict__ wymax,
                                                float* __restrict__ out) {
  const int t = threadIdx.x;
  const int w = t >> 6, lane = t & 63;

  if (blockIdx.x < 128) {
    // ---------- argmax/ymax, one wave per row, + fused y->out copy ----------
    const int b = blockIdx.x * 4 + w;
    const float* yr = y + (size_t)b * CC;
    float bv = -INFINITY; int bi = 0;
    #pragma unroll
    for (int k = 0; k < 4; ++k) {
      const int c4 = (lane + k * 64) * 4;   // ascending per lane -> '>' keeps lowest
      if (c4 < CC) {
        const float4 v = *(const float4*)(yr + c4);
        if (v.x > bv) { bv = v.x; bi = c4; }
        if (v.y > bv) { bv = v.y; bi = c4 + 1; }
        if (v.z > bv) { bv = v.z; bi = c4 + 2; }
        if (v.w > bv) { bv = v.w; bi = c4 + 3; }
        f4u vv = {v.x, v.y, v.z, v.w};        // 4B-aligned dwordx4 store
        *(f4u*)(out + (size_t)b * (CC + 1) + c4) = vv;
      }
    }
    #pragma unroll
    for (int off = 32; off > 0; off >>= 1) {
      const float ov = __shfl_down(bv, off);
      const int   oi = __shfl_down(bi, off);
      if (ov > bv || (ov == bv && oi < bi)) { bv = ov; bi = oi; }
    }
    if (lane == 0) { wj[b] = bi; wymax[b] = bv; }
  } else {
    // ---------- transpose kW -> Wt (LDS-staged) + fp32 norm chunks ----------
    __shared__ float nsum[4][64];
    __shared__ __align__(16) unsigned short tile[64][72];  // 64c x 64d (+pad)
    const int blk = blockIdx.x - 128;    // 0..127
    const int cs = blk & 15, dc = blk >> 4;   // 16 c-slices x 8 d-chunks
    const int c0 = cs * 64, d0 = dc * 64;
    const int c = c0 + lane;
    const bool cok = (c < CC);
    float s = 0.f;
    #pragma unroll 8
    for (int it = 0; it < 16; ++it) {
      const int dd = w + it * 4;                    // 0..63
      const float v = cok ? kW[(size_t)(d0 + dd) * CC + c] : 0.f;
      s += v * v;
      tile[lane][dd] = f2bf(v);
    }
    nsum[w][lane] = s;
    __syncthreads();
    if (w == 0)                                      // c-major norm chunk
      normc[(size_t)c * NDC + dc] = nsum[0][lane] + nsum[1][lane] + nsum[2][lane] + nsum[3][lane];
    // coalesced 16B writes of the transposed tile
    #pragma unroll
    for (int k = 0; k < 2; ++k) {
      const int lin = t * 2 + k;                    // 0..511
      const int cc = lin >> 3, ch = lin & 7;
      *(us8*)(Wt + (size_t)(c0 + cc) * RP + d0 + ch * 8) =
          *(const us8*)(&tile[cc][ch * 8]);
    }
  }
}

__global__ __launch_bounds__(256) void lm_gemm(const unsigned short* __restrict__ Wt,
                                               const float* __restrict__ y,
                                               const float* __restrict__ normc,
                                               const int* __restrict__ wj,
                                               const float* __restrict__ wymax,
                                               float* __restrict__ out) {
  const int t = threadIdx.x;
  const int lane = t & 63;
  const int tile = blockIdx.x * 4 + (t >> 6);   // 0..2047
  const int m0 = (tile >> 6) * 16;              // 32 m-tiles (batch)
  const int n0 = (tile & 63) * 16;              // 64 n-tiles (classes)

  const int fr = lane & 15;            // A: m-row / B: n-row / C: col
  const int quad = lane >> 4;          // A/B: k-offset quad*8; C: row quad*4+reg

  const int ja = wj[m0 + fr];          // A-side: row j of Wt IS column j of kW
  const unsigned short* ap = Wt + (size_t)ja * RP + quad * 8;
  const unsigned short* bp = Wt + (size_t)(n0 + fr) * RP + quad * 8;

  // register-prefetch the whole K-slab (32 independent 16B loads), then MFMA
  short8 af[16], bf[16];
  #pragma unroll
  for (int k = 0; k < 16; ++k) {
    af[k] = *(const short8*)(ap + k * 32);
    bf[k] = *(const short8*)(bp + k * 32);
  }
  // two accumulators: dependent-MFMA chain depth 8, not 16
  f32x4 a0 = {0.f, 0.f, 0.f, 0.f}, a1 = {0.f, 0.f, 0.f, 0.f};
  #pragma unroll
  for (int k = 0; k < 16; k += 2) {
    a0 = __builtin_amdgcn_mfma_f32_16x16x32_bf16(af[k],     bf[k],     a0, 0, 0, 0);
    a1 = __builtin_amdgcn_mfma_f32_16x16x32_bf16(af[k + 1], bf[k + 1], a1, 0, 0, 0);
  }
  const f32x4 acc = a0 + a1;

  // ---- fused epilogue: candidates + butterfly row-max + atomicMax ----
  const int col = n0 + fr;             // class
  const bool cok = (col < CC);
  float nc = 0.f;
  if (cok) {
    const float4 na = *(const float4*)(normc + (size_t)col * NDC);
    const float4 nb = *(const float4*)(normc + (size_t)col * NDC + 4);
    nc = (na.x + na.y) + (na.z + na.w) + (nb.x + nb.y) + (nb.z + nb.w);
  }

  #pragma unroll
  for (int r = 0; r < 4; ++r) {
    const int row = m0 + quad * 4 + r; // batch
    float cd = -INFINITY;
    if (cok) {
      const int jr = wj[row];
      const float4 ja4 = *(const float4*)(normc + (size_t)jr * NDC);
      const float4 jb4 = *(const float4*)(normc + (size_t)jr * NDC + 4);
      const float nj = (ja4.x + ja4.y) + (ja4.z + ja4.w) + (jb4.x + jb4.y) + (jb4.z + jb4.w);
      const float yv = y[(size_t)row * CC + col];
      const float ym = wymax[row];
      const float k2 = nj + nc - 2.f * acc[r];
      cd = (yv == ym) ? -INFINITY : yv + EPSF * sqrtf(fmaxf(k2, 0.f) + 1e-10f);
    }
    #pragma unroll
    for (int m = 1; m < 16; m <<= 1)   // reduce over the 16 cols (same quad group)
      cd = fmaxf(cd, __shfl_xor(cd, m));
    if (fr == 0)                        // positive floats: int compare == float compare
      atomicMax((int*)(out + (size_t)row * (CC + 1) + CC), __float_as_int(cd));
  }
}

extern "C" void kernel_launch(void* const* d_in, const int* in_sizes, int n_in,
                              void* d_out, int out_size, void* d_ws, size_t ws_size,
                              hipStream_t stream) {
  const float* y  = (const float*)d_in[0];   // [512, 1000]
  const float* kW = (const float*)d_in[1];   // [512, 1000]
  float* out = (float*)d_out;                // [512, 1001]

  char* ws = (char*)d_ws;
  unsigned short* Wt = (unsigned short*)(ws);                   // 1024*528*2 = 1081 KB
  float* normc       = (float*)(ws + (1088 << 10));             // 32 KB
  int*   wjp         = (int*)(ws + (1120 << 10));               // 2 KB
  float* wymaxp      = (float*)(ws + (1122 << 10));             // 2 KB

  lm_build<<<256, 256, 0, stream>>>(y, kW, Wt, normc, wjp, wymaxp, out);
  lm_gemm<<<512, 256, 0, stream>>>(Wt, y, normc, wjp, wymaxp, out);
}